// Round 1
// baseline (17199.892 us; speedup 1.0000x reference)
//
#include <hip/hip_runtime.h>

#define Bn   128
#define Tn   512
#define Kn   12
#define Hn   256
#define NWG  256
#define ARR      32768            // 128*256 elements per state array
#define SSTRIDE  (4*ARR)          // ushorts per state buffer (h_hi,h_lo,c_hi,c_lo)

typedef __attribute__((ext_vector_type(8))) short bf16x8;
typedef __attribute__((ext_vector_type(4))) float f32x4;

__device__ inline unsigned short f2bf(float x) {
  union { float f; unsigned u; } v; v.f = x;
  unsigned r = v.u + 0x7fffu + ((v.u >> 16) & 1u);
  return (unsigned short)(r >> 16);
}
__device__ inline float bf2f(unsigned short h) {
  union { unsigned u; float f; } v; v.u = ((unsigned)h) << 16;
  return v.f;
}
__device__ inline float sigmf(float x) { return 1.0f / (1.0f + __expf(-x)); }

__global__ void __launch_bounds__(256, 1) mtlstm_kernel(
    const float* __restrict__ xd, const float* __restrict__ dtp,
    const float* __restrict__ wih, const float* __restrict__ whh,
    const float* __restrict__ bias, const float* __restrict__ wdc,
    const float* __restrict__ bdc, unsigned char* __restrict__ ws)
{
  __shared__ __align__(16) float xs_lds[32 * Kn];
  __shared__ __align__(16) float dt_lds[32 * Kn];
  __shared__ float g_lds[32 * 16];      // activated gates [b_local][jj*4+g]
  __shared__ float dsum_lds[32 * 48];   // decomp contribs [b_local][jj][k]

  unsigned* cnt = (unsigned*)ws;
  unsigned* flg = cnt + 1;
  unsigned short* state = (unsigned short*)(ws + 128);
  float* h_final = (float*)(ws + 128 + 2 * SSTRIDE * 2);

  const int tid = threadIdx.x;
  const int wv  = tid >> 6;        // wave 0: gates(h); waves 1..3: decomp(c)
  const int l   = tid & 63;
  const int n   = l & 15;          // MFMA col / A-row within tile
  const int oct = l >> 4;          // k-octet

  const int wgid = blockIdx.x;
  const int bg = wgid >> 6;        // batch group 0..3 (32 b each)
  const int j0 = (wgid & 63) * 4;  // 4 j-columns per WG

  // ---- one-time weight setup: per-lane 16 cols x 256 k, split hi/lo bf16 ----
  const float* rowp;
  float biasv;
  int kd = 0, jjd = 0;
  float wx[12];
  if (wv == 0) {
    int jj = n >> 2, g = n & 3;
    int grow = g * Hn + j0 + jj;
    rowp = whh + (size_t)grow * Hn;
    biasv = bias[grow];
#pragma unroll
    for (int kk = 0; kk < 12; ++kk) wx[kk] = wih[grow * 12 + kk];
  } else {
    int q = (wv - 1) * 16 + n;     // 0..47
    int jj = q / 12;
    int k  = q - jj * 12;
    kd = k; jjd = jj;
    rowp = wdc + ((size_t)k * Hn + (j0 + jj)) * Hn;
    biasv = bdc[k * Hn + j0 + jj];
#pragma unroll
    for (int kk = 0; kk < 12; ++kk) wx[kk] = 0.f;
  }

  bf16x8 wh[8], wl[8];
#pragma unroll
  for (int ks = 0; ks < 8; ++ks) {
    const float* p = rowp + ks * 32 + oct * 8;
#pragma unroll
    for (int e = 0; e < 8; ++e) {
      float x = p[e];
      unsigned short hi = f2bf(x);
      unsigned short lo = f2bf(x - bf2f(hi));
      wh[ks][e] = (short)hi;
      wl[ks][e] = (short)lo;
    }
  }

  const int aoff0 = (bg * 32 + n) * Hn + oct * 8;  // M-tile 0 A offset
  const int aoff1 = aoff0 + 16 * Hn;               // M-tile 1
  const int hsel  = (wv == 0) ? 0 : 2 * ARR;       // h arrays vs c arrays

  float c_reg = 0.0f;     // exact fp32 c for owned (b,j), threads 0..127
  unsigned gen = 0;

  for (int t = 0; t < Tn; ++t) {
    const unsigned short* sb = state + (t & 1) * SSTRIDE + hsel;

    // stage x_t, dt_t for this WG's 32 b's
    if (tid < 96) {
      int bl = tid / 3, ch = tid % 3;
      float4 v = *(const float4*)(xd + ((size_t)(bg * 32 + bl) * Tn + t) * Kn + ch * 4);
      *(float4*)(&xs_lds[bl * 12 + ch * 4]) = v;
    } else if (tid < 192) {
      int q2 = tid - 96;
      int bl = q2 / 3, ch = q2 % 3;
      float4 v = *(const float4*)(dtp + ((size_t)(bg * 32 + bl) * Tn + t) * Kn + ch * 4);
      *(float4*)(&dt_lds[bl * 12 + ch * 4]) = v;
    }

    // ---- GEMM: 2 M-tiles x 1 N-tile, K=256, split-bf16 (3 MFMA) ----
    f32x4 acc0 = {0.f, 0.f, 0.f, 0.f};
    f32x4 acc1 = {0.f, 0.f, 0.f, 0.f};
#pragma unroll
    for (int ks = 0; ks < 8; ++ks) {
      int o = ks * 32;
      bf16x8 a0h = *(const bf16x8*)(sb + aoff0 + o);
      bf16x8 a1h = *(const bf16x8*)(sb + aoff1 + o);
      bf16x8 a0l = *(const bf16x8*)(sb + ARR + aoff0 + o);
      bf16x8 a1l = *(const bf16x8*)(sb + ARR + aoff1 + o);
      acc0 = __builtin_amdgcn_mfma_f32_16x16x32_bf16(a0h, wh[ks], acc0, 0, 0, 0);
      acc1 = __builtin_amdgcn_mfma_f32_16x16x32_bf16(a1h, wh[ks], acc1, 0, 0, 0);
      acc0 = __builtin_amdgcn_mfma_f32_16x16x32_bf16(a0h, wl[ks], acc0, 0, 0, 0);
      acc1 = __builtin_amdgcn_mfma_f32_16x16x32_bf16(a1h, wl[ks], acc1, 0, 0, 0);
      acc0 = __builtin_amdgcn_mfma_f32_16x16x32_bf16(a0l, wh[ks], acc0, 0, 0, 0);
      acc1 = __builtin_amdgcn_mfma_f32_16x16x32_bf16(a1l, wh[ks], acc1, 0, 0, 0);
    }

    __syncthreads();   // x/dt staged; LDS phase boundary

    // ---- epilogue: D layout row=(oct*4+r) (=b_local within tile), col=n ----
    if (wv == 0) {
      int g = n & 3;
#pragma unroll
      for (int mt = 0; mt < 2; ++mt) {
        f32x4 a = mt ? acc1 : acc0;
#pragma unroll
        for (int r = 0; r < 4; ++r) {
          int bl = mt * 16 + oct * 4 + r;
          float xwv = 0.f;
#pragma unroll
          for (int kk = 0; kk < 12; ++kk) xwv += xs_lds[bl * 12 + kk] * wx[kk];
          float v = a[r] + biasv + xwv;
          float act = (g == 2) ? tanhf(v) : sigmf(v);
          g_lds[bl * 16 + n] = act;
        }
      }
    } else {
#pragma unroll
      for (int mt = 0; mt < 2; ++mt) {
        f32x4 a = mt ? acc1 : acc0;
#pragma unroll
        for (int r = 0; r < 4; ++r) {
          int bl = mt * 16 + oct * 4 + r;
          float v = a[r] + biasv;
          float cs = tanhf(v);
          float dtv = dt_lds[bl * 12 + kd];
          float coef = 1.0f / __logf(2.718281828459045f + dtv) - 1.0f;
          dsum_lds[bl * 48 + jjd * 12 + kd] = cs * coef;
        }
      }
    }
    __syncthreads();

    // ---- state update by owner threads (exact fp32 c kept in register) ----
    if (tid < 128) {
      int bl = tid >> 2, jj = tid & 3;
      float iv = g_lds[bl * 16 + jj * 4 + 0];
      float fv = g_lds[bl * 16 + jj * 4 + 1];
      float gv = g_lds[bl * 16 + jj * 4 + 2];
      float ov = g_lds[bl * 16 + jj * 4 + 3];
      float S = 0.f;
#pragma unroll
      for (int k = 0; k < 12; ++k) S += dsum_lds[bl * 48 + jj * 12 + k];
      float cst = c_reg + S;
      float cn = fv * cst + iv * gv;
      float hn = ov * tanhf(cn);
      c_reg = cn;
      unsigned short hh = f2bf(hn);
      unsigned short hl = f2bf(hn - bf2f(hh));
      unsigned short ch = f2bf(cn);
      unsigned short cl = f2bf(cn - bf2f(ch));
      unsigned short* nb = state + ((t + 1) & 1) * SSTRIDE;
      int idx = (bg * 32 + bl) * Hn + (j0 + jj);
      nb[idx]           = hh;
      nb[ARR + idx]     = hl;
      nb[2 * ARR + idx] = ch;
      nb[3 * ARR + idx] = cl;
      if (t == Tn - 1) h_final[idx] = hn;
    }

    // ---- grid barrier (sense via monotone generation) ----
    ++gen;
    __syncthreads();   // drains vmcnt: all WG stores are in L2 before fence
    if (tid == 0) {
      __threadfence();  // device-scope release: writeback L2 for cross-XCD
      unsigned old = __hip_atomic_fetch_add(cnt, 1u, __ATOMIC_ACQ_REL,
                                            __HIP_MEMORY_SCOPE_AGENT);
      if (old == NWG - 1) {
        __hip_atomic_store(cnt, 0u, __ATOMIC_RELAXED, __HIP_MEMORY_SCOPE_AGENT);
        __hip_atomic_store(flg, gen, __ATOMIC_RELEASE, __HIP_MEMORY_SCOPE_AGENT);
      } else {
        while (__hip_atomic_load(flg, __ATOMIC_RELAXED,
                                 __HIP_MEMORY_SCOPE_AGENT) < gen) {
          __builtin_amdgcn_s_sleep(1);
        }
        __threadfence();  // acquire: invalidate stale L1/L2 before next reads
      }
    }
    __syncthreads();
  }
}

__global__ void out_gemv(const float* __restrict__ hf, const float* __restrict__ lw,
                         const float* __restrict__ lb, float* __restrict__ out)
{
  int b = blockIdx.x;
  int l = threadIdx.x;
  const float* row = hf + b * Hn;
  float s = row[l] * lw[l] + row[l + 64] * lw[l + 64]
          + row[l + 128] * lw[l + 128] + row[l + 192] * lw[l + 192];
#pragma unroll
  for (int off = 32; off > 0; off >>= 1) s += __shfl_down(s, off, 64);
  if (l == 0) out[b] = s + lb[0];
}

extern "C" void kernel_launch(void* const* d_in, const int* in_sizes, int n_in,
                              void* d_out, int out_size, void* d_ws, size_t ws_size,
                              hipStream_t stream)
{
  const float* xd   = (const float*)d_in[0];
  const float* dtp  = (const float*)d_in[1];
  const float* wih  = (const float*)d_in[2];
  const float* whh  = (const float*)d_in[3];
  const float* bias = (const float*)d_in[4];
  const float* wdc  = (const float*)d_in[5];
  const float* bdc  = (const float*)d_in[6];
  const float* lw   = (const float*)d_in[7];
  const float* lb   = (const float*)d_in[8];
  float* out = (float*)d_out;
  unsigned char* ws = (unsigned char*)d_ws;

  // zero barrier + both state buffers (ws is poisoned 0xAA each call)
  hipMemsetAsync(ws, 0, 128 + 2 * SSTRIDE * 2, stream);

  void* args[] = { (void*)&xd, (void*)&dtp, (void*)&wih, (void*)&whh,
                   (void*)&bias, (void*)&wdc, (void*)&bdc, (void*)&ws };
  hipLaunchCooperativeKernel((const void*)mtlstm_kernel, dim3(NWG), dim3(256),
                             args, 0, stream);

  const float* hf = (const float*)(ws + 128 + 2 * SSTRIDE * 2);
  out_gemv<<<dim3(Bn), dim3(64), 0, stream>>>(hf, lw, lb, out);
}

// Round 4
// 14840.355 us; speedup vs baseline: 1.1590x; 1.1590x over previous
//
#include <hip/hip_runtime.h>

#define Bn   128
#define Tn   512
#define Kn   12
#define Hn   256
#define NWG  256
#define ARR      32768            // 128*256 elements per state array
#define SSTRIDE  (4*ARR)          // ushorts per state buffer (h_hi,h_lo,c_hi,c_lo)

typedef __attribute__((ext_vector_type(8))) short bf16x8;
typedef __attribute__((ext_vector_type(4))) float f32x4;

__device__ inline unsigned short f2bf(float x) {
  union { float f; unsigned u; } v; v.f = x;
  unsigned r = v.u + 0x7fffu + ((v.u >> 16) & 1u);
  return (unsigned short)(r >> 16);
}
__device__ inline float bf2f(unsigned short h) {
  union { unsigned u; float f; } v; v.u = ((unsigned)h) << 16;
  return v.f;
}
__device__ inline float sigmf(float x) { return 1.0f / (1.0f + __expf(-x)); }

// ROUND-1 PROVEN STRUCTURE (absmax 0.0), with exactly ONE change: owners are
// repacked (tid<32, one batch row each, 4 j-cols) and write state as packed
// 8B agent-scope sc1 atomic stores instead of 4 scattered 2B plain stores.
// Rationale: round-1 WRITE_SIZE showed 4x partial-line write amplification;
// scattered ushorts leave ~256KB/step dirty in per-XCD L2s, making each WG's
// release fence (buffer_wbl2) expensive. sc1 write-through stores keep L2
// clean; the fence protocol itself is unchanged and proven.
__global__ void __launch_bounds__(256, 1) mtlstm_kernel(
    const float* __restrict__ xd, const float* __restrict__ dtp,
    const float* __restrict__ wih, const float* __restrict__ whh,
    const float* __restrict__ bias, const float* __restrict__ wdc,
    const float* __restrict__ bdc, unsigned char* __restrict__ ws)
{
  __shared__ __align__(16) float xs_lds[32 * Kn];
  __shared__ __align__(16) float dt_lds[32 * Kn];
  __shared__ float g_lds[32 * 16];      // activated gates [b_local][jj*4+g]
  __shared__ float dsum_lds[32 * 48];   // decomp contribs [b_local][jj][k]

  unsigned* cnt = (unsigned*)ws;
  unsigned* flg = cnt + 1;
  unsigned short* state = (unsigned short*)(ws + 128);
  float* h_final = (float*)(ws + 128 + 2 * SSTRIDE * 2);

  const int tid = threadIdx.x;
  const int wv  = tid >> 6;        // wave 0: gates(h); waves 1..3: decomp(c)
  const int l   = tid & 63;
  const int n   = l & 15;          // MFMA col / A-row within tile
  const int oct = l >> 4;          // k-octet

  const int wgid = blockIdx.x;
  const int bg = wgid >> 6;        // batch group 0..3 (32 b each)
  const int j0 = (wgid & 63) * 4;  // 4 j-columns per WG

  // ---- one-time weight setup: per-lane 16 cols x 256 k, split hi/lo bf16 ----
  const float* rowp;
  float biasv;
  int kd = 0, jjd = 0;
  float wx[12];
  if (wv == 0) {
    int jj = n >> 2, g = n & 3;
    int grow = g * Hn + j0 + jj;
    rowp = whh + (size_t)grow * Hn;
    biasv = bias[grow];
#pragma unroll
    for (int kk = 0; kk < 12; ++kk) wx[kk] = wih[grow * 12 + kk];
  } else {
    int q = (wv - 1) * 16 + n;     // 0..47
    int jj = q / 12;
    int k  = q - jj * 12;
    kd = k; jjd = jj;
    rowp = wdc + ((size_t)k * Hn + (j0 + jj)) * Hn;
    biasv = bdc[k * Hn + j0 + jj];
#pragma unroll
    for (int kk = 0; kk < 12; ++kk) wx[kk] = 0.f;
  }

  bf16x8 wh[8], wl[8];
#pragma unroll
  for (int ks = 0; ks < 8; ++ks) {
    const float* p = rowp + ks * 32 + oct * 8;
#pragma unroll
    for (int e = 0; e < 8; ++e) {
      float x = p[e];
      unsigned short hi = f2bf(x);
      unsigned short lo = f2bf(x - bf2f(hi));
      wh[ks][e] = (short)hi;
      wl[ks][e] = (short)lo;
    }
  }

  const int aoff0 = (bg * 32 + n) * Hn + oct * 8;  // M-tile 0 A offset
  const int aoff1 = aoff0 + 16 * Hn;               // M-tile 1
  const int hsel  = (wv == 0) ? 0 : 2 * ARR;       // h arrays vs c arrays

  float c_reg[4] = {0.f, 0.f, 0.f, 0.f};  // exact fp32 c, owners tid<32 (4 j each)
  unsigned gen = 0;

  for (int t = 0; t < Tn; ++t) {
    const unsigned short* sb = state + (t & 1) * SSTRIDE + hsel;

    // stage x_t, dt_t for this WG's 32 b's
    if (tid < 96) {
      int bl = tid / 3, ch = tid % 3;
      float4 v = *(const float4*)(xd + ((size_t)(bg * 32 + bl) * Tn + t) * Kn + ch * 4);
      *(float4*)(&xs_lds[bl * 12 + ch * 4]) = v;
    } else if (tid < 192) {
      int q2 = tid - 96;
      int bl = q2 / 3, ch = q2 % 3;
      float4 v = *(const float4*)(dtp + ((size_t)(bg * 32 + bl) * Tn + t) * Kn + ch * 4);
      *(float4*)(&dt_lds[bl * 12 + ch * 4]) = v;
    }

    // ---- GEMM: 2 M-tiles x 1 N-tile, K=256, split-bf16 (3 MFMA) ----
    f32x4 acc0 = {0.f, 0.f, 0.f, 0.f};
    f32x4 acc1 = {0.f, 0.f, 0.f, 0.f};
#pragma unroll
    for (int ks = 0; ks < 8; ++ks) {
      int o = ks * 32;
      bf16x8 a0h = *(const bf16x8*)(sb + aoff0 + o);
      bf16x8 a1h = *(const bf16x8*)(sb + aoff1 + o);
      bf16x8 a0l = *(const bf16x8*)(sb + ARR + aoff0 + o);
      bf16x8 a1l = *(const bf16x8*)(sb + ARR + aoff1 + o);
      acc0 = __builtin_amdgcn_mfma_f32_16x16x32_bf16(a0h, wh[ks], acc0, 0, 0, 0);
      acc1 = __builtin_amdgcn_mfma_f32_16x16x32_bf16(a1h, wh[ks], acc1, 0, 0, 0);
      acc0 = __builtin_amdgcn_mfma_f32_16x16x32_bf16(a0h, wl[ks], acc0, 0, 0, 0);
      acc1 = __builtin_amdgcn_mfma_f32_16x16x32_bf16(a1h, wl[ks], acc1, 0, 0, 0);
      acc0 = __builtin_amdgcn_mfma_f32_16x16x32_bf16(a0l, wh[ks], acc0, 0, 0, 0);
      acc1 = __builtin_amdgcn_mfma_f32_16x16x32_bf16(a1l, wh[ks], acc1, 0, 0, 0);
    }

    __syncthreads();   // x/dt staged; LDS phase boundary

    // ---- epilogue: D layout row=(oct*4+r) (=b_local within tile), col=n ----
    if (wv == 0) {
      int g = n & 3;
#pragma unroll
      for (int mt = 0; mt < 2; ++mt) {
        f32x4 a = mt ? acc1 : acc0;
#pragma unroll
        for (int r = 0; r < 4; ++r) {
          int bl = mt * 16 + oct * 4 + r;
          float xwv = 0.f;
#pragma unroll
          for (int kk = 0; kk < 12; ++kk) xwv += xs_lds[bl * 12 + kk] * wx[kk];
          float v = a[r] + biasv + xwv;
          float act = (g == 2) ? tanhf(v) : sigmf(v);
          g_lds[bl * 16 + n] = act;
        }
      }
    } else {
#pragma unroll
      for (int mt = 0; mt < 2; ++mt) {
        f32x4 a = mt ? acc1 : acc0;
#pragma unroll
        for (int r = 0; r < 4; ++r) {
          int bl = mt * 16 + oct * 4 + r;
          float v = a[r] + biasv;
          float cs = tanhf(v);
          float dtv = dt_lds[bl * 12 + kd];
          float coef = 1.0f / __logf(2.718281828459045f + dtv) - 1.0f;
          dsum_lds[bl * 48 + jjd * 12 + kd] = cs * coef;
        }
      }
    }
    __syncthreads();

    // ---- state update: tid<32, one batch row each, packed 8B sc1 stores ----
    if (tid < 32) {
      int b = tid;
      union P { unsigned short u[4]; unsigned long long q; } ph, pl, pc, pq;
#pragma unroll
      for (int jj = 0; jj < 4; ++jj) {
        float iv = g_lds[b * 16 + jj * 4 + 0];
        float fv = g_lds[b * 16 + jj * 4 + 1];
        float gv = g_lds[b * 16 + jj * 4 + 2];
        float ov = g_lds[b * 16 + jj * 4 + 3];
        float S = 0.f;
#pragma unroll
        for (int k = 0; k < 12; ++k) S += dsum_lds[b * 48 + jj * 12 + k];
        float cst = c_reg[jj] + S;
        float cn = fv * cst + iv * gv;
        float hn = ov * tanhf(cn);
        c_reg[jj] = cn;
        ph.u[jj] = f2bf(hn);
        pl.u[jj] = f2bf(hn - bf2f(ph.u[jj]));
        pc.u[jj] = f2bf(cn);
        pq.u[jj] = f2bf(cn - bf2f(pc.u[jj]));
        if (t == Tn - 1)
          h_final[(size_t)(bg * 32 + b) * Hn + j0 + jj] = hn;
      }
      unsigned long long* db = (unsigned long long*)state
          + (size_t)((t + 1) & 1) * (SSTRIDE / 4)
          + (size_t)(bg * 32 + b) * 64 + (j0 >> 2);
      __hip_atomic_store(db + 0 * (ARR / 4), ph.q, __ATOMIC_RELAXED, __HIP_MEMORY_SCOPE_AGENT);
      __hip_atomic_store(db + 1 * (ARR / 4), pl.q, __ATOMIC_RELAXED, __HIP_MEMORY_SCOPE_AGENT);
      __hip_atomic_store(db + 2 * (ARR / 4), pc.q, __ATOMIC_RELAXED, __HIP_MEMORY_SCOPE_AGENT);
      __hip_atomic_store(db + 3 * (ARR / 4), pq.q, __ATOMIC_RELAXED, __HIP_MEMORY_SCOPE_AGENT);
    }

    // ---- grid barrier (round-1 proven protocol, verbatim) ----
    ++gen;
    __syncthreads();   // drains vmcnt: all WG stores are in L2/L3 before fence
    if (tid == 0) {
      __threadfence();  // device-scope release: writeback L2 (clean for state now)
      unsigned old = __hip_atomic_fetch_add(cnt, 1u, __ATOMIC_ACQ_REL,
                                            __HIP_MEMORY_SCOPE_AGENT);
      if (old == NWG - 1) {
        __hip_atomic_store(cnt, 0u, __ATOMIC_RELAXED, __HIP_MEMORY_SCOPE_AGENT);
        __hip_atomic_store(flg, gen, __ATOMIC_RELEASE, __HIP_MEMORY_SCOPE_AGENT);
      } else {
        while (__hip_atomic_load(flg, __ATOMIC_RELAXED,
                                 __HIP_MEMORY_SCOPE_AGENT) < gen) {
          __builtin_amdgcn_s_sleep(1);
        }
        __threadfence();  // acquire: invalidate stale L1/L2 before next reads
      }
    }
    __syncthreads();
  }
}

__global__ void out_gemv(const float* __restrict__ hf, const float* __restrict__ lw,
                         const float* __restrict__ lb, float* __restrict__ out)
{
  int b = blockIdx.x;
  int l = threadIdx.x;
  const float* row = hf + b * Hn;
  float s = row[l] * lw[l] + row[l + 64] * lw[l + 64]
          + row[l + 128] * lw[l + 128] + row[l + 192] * lw[l + 192];
#pragma unroll
  for (int off = 32; off > 0; off >>= 1) s += __shfl_down(s, off, 64);
  if (l == 0) out[b] = s + lb[0];
}

extern "C" void kernel_launch(void* const* d_in, const int* in_sizes, int n_in,
                              void* d_out, int out_size, void* d_ws, size_t ws_size,
                              hipStream_t stream)
{
  const float* xd   = (const float*)d_in[0];
  const float* dtp  = (const float*)d_in[1];
  const float* wih  = (const float*)d_in[2];
  const float* whh  = (const float*)d_in[3];
  const float* bias = (const float*)d_in[4];
  const float* wdc  = (const float*)d_in[5];
  const float* bdc  = (const float*)d_in[6];
  const float* lw   = (const float*)d_in[7];
  const float* lb   = (const float*)d_in[8];
  float* out = (float*)d_out;
  unsigned char* ws = (unsigned char*)d_ws;

  // zero barrier + both state buffers (ws is poisoned 0xAA each call)
  hipMemsetAsync(ws, 0, 128 + 2 * SSTRIDE * 2, stream);

  void* args[] = { (void*)&xd, (void*)&dtp, (void*)&wih, (void*)&whh,
                   (void*)&bias, (void*)&wdc, (void*)&bdc, (void*)&ws };
  hipLaunchCooperativeKernel((const void*)mtlstm_kernel, dim3(NWG), dim3(256),
                             args, 0, stream);

  const float* hf = (const float*)(ws + 128 + 2 * SSTRIDE * 2);
  out_gemv<<<dim3(Bn), dim3(64), 0, stream>>>(hf, lw, lb, out);
}

// Round 6
// 6955.507 us; speedup vs baseline: 2.4728x; 2.1336x over previous
//
#include <hip/hip_runtime.h>

#define Bn   128
#define Tn   512
#define Kn   12
#define Hn   256
#define NWG  256
#define ARR      32768            // 128*256 elements per state array
#define SSTRIDE  (4*ARR)          // ushorts per state buffer (h_hi,h_lo,c_hi,c_lo)

typedef __attribute__((ext_vector_type(8))) short bf16x8;
typedef __attribute__((ext_vector_type(4))) float f32x4;

__device__ inline unsigned short f2bf(float x) {
  union { float f; unsigned u; } v; v.f = x;
  unsigned r = v.u + 0x7fffu + ((v.u >> 16) & 1u);
  return (unsigned short)(r >> 16);
}
__device__ inline float bf2f(unsigned short h) {
  union { unsigned u; float f; } v; v.u = ((unsigned)h) << 16;
  return v.f;
}
__device__ inline float sigmf(float x) { return 1.0f / (1.0f + __expf(-x)); }

// ROUND-4 PROVEN KERNEL (absmax 0.0, 14.8ms) with ONE change: the grid
// barrier drops both __threadfence()s (wbl2+inv pairs) and the ACQ_REL RMW.
// Why sound: state stores are sc0sc1 write-through atomics -> no dirty state
// in any per-XCD L2 (nothing to write back); __syncthreads drains vmcnt, so
// every WG's stores are ack'd at the coherence point BEFORE its arrival RMW.
// Therefore flag==gen implies all step-t stores are globally visible; the
// single ACQUIRE agent fence (buffer_inv, no wbl2) drops stale vL1/L2 lines
// before the next step's plain cached state loads.
// (Round-5 lesson: deferred-drain inline-asm loads fault — async dst can
// clobber later asm loads' address regs. Round-2/3 lesson: relaxed agent
// atomic loads still hit stale vL1 -> cached loads + per-step inv instead.)
__global__ void __launch_bounds__(256, 1) mtlstm_kernel(
    const float* __restrict__ xd, const float* __restrict__ dtp,
    const float* __restrict__ wih, const float* __restrict__ whh,
    const float* __restrict__ bias, const float* __restrict__ wdc,
    const float* __restrict__ bdc, unsigned char* __restrict__ ws)
{
  __shared__ __align__(16) float xs_lds[32 * Kn];
  __shared__ __align__(16) float dt_lds[32 * Kn];
  __shared__ float g_lds[32 * 16];      // activated gates [b_local][jj*4+g]
  __shared__ float dsum_lds[32 * 48];   // decomp contribs [b_local][jj][k]

  unsigned* cnt = (unsigned*)ws;
  unsigned* flg = cnt + 1;
  unsigned short* state = (unsigned short*)(ws + 128);
  float* h_final = (float*)(ws + 128 + 2 * SSTRIDE * 2);

  const int tid = threadIdx.x;
  const int wv  = tid >> 6;        // wave 0: gates(h); waves 1..3: decomp(c)
  const int l   = tid & 63;
  const int n   = l & 15;          // MFMA col / A-row within tile
  const int oct = l >> 4;          // k-octet

  const int wgid = blockIdx.x;
  const int bg = wgid >> 6;        // batch group 0..3 (32 b each)
  const int j0 = (wgid & 63) * 4;  // 4 j-columns per WG

  // ---- one-time weight setup: per-lane 16 cols x 256 k, split hi/lo bf16 ----
  const float* rowp;
  float biasv;
  int kd = 0, jjd = 0;
  float wx[12];
  if (wv == 0) {
    int jj = n >> 2, g = n & 3;
    int grow = g * Hn + j0 + jj;
    rowp = whh + (size_t)grow * Hn;
    biasv = bias[grow];
#pragma unroll
    for (int kk = 0; kk < 12; ++kk) wx[kk] = wih[grow * 12 + kk];
  } else {
    int q = (wv - 1) * 16 + n;     // 0..47
    int jj = q / 12;
    int k  = q - jj * 12;
    kd = k; jjd = jj;
    rowp = wdc + ((size_t)k * Hn + (j0 + jj)) * Hn;
    biasv = bdc[k * Hn + j0 + jj];
#pragma unroll
    for (int kk = 0; kk < 12; ++kk) wx[kk] = 0.f;
  }

  bf16x8 wh[8], wl[8];
#pragma unroll
  for (int ks = 0; ks < 8; ++ks) {
    const float* p = rowp + ks * 32 + oct * 8;
#pragma unroll
    for (int e = 0; e < 8; ++e) {
      float x = p[e];
      unsigned short hi = f2bf(x);
      unsigned short lo = f2bf(x - bf2f(hi));
      wh[ks][e] = (short)hi;
      wl[ks][e] = (short)lo;
    }
  }

  const int aoff0 = (bg * 32 + n) * Hn + oct * 8;  // M-tile 0 A offset
  const int aoff1 = aoff0 + 16 * Hn;               // M-tile 1
  const int hsel  = (wv == 0) ? 0 : 2 * ARR;       // h arrays vs c arrays

  float c_reg[4] = {0.f, 0.f, 0.f, 0.f};  // exact fp32 c, owners tid<32 (4 j each)
  unsigned gen = 0;

  for (int t = 0; t < Tn; ++t) {
    const unsigned short* sb = state + (t & 1) * SSTRIDE + hsel;

    // stage x_t, dt_t for this WG's 32 b's (read-only inputs: plain cached loads)
    if (tid < 96) {
      int bl = tid / 3, ch = tid % 3;
      float4 v = *(const float4*)(xd + ((size_t)(bg * 32 + bl) * Tn + t) * Kn + ch * 4);
      *(float4*)(&xs_lds[bl * 12 + ch * 4]) = v;
    } else if (tid < 192) {
      int q2 = tid - 96;
      int bl = q2 / 3, ch = q2 % 3;
      float4 v = *(const float4*)(dtp + ((size_t)(bg * 32 + bl) * Tn + t) * Kn + ch * 4);
      *(float4*)(&dt_lds[bl * 12 + ch * 4]) = v;
    }

    // ---- GEMM: 2 M-tiles x 1 N-tile, K=256, split-bf16 (3 MFMA) ----
    f32x4 acc0 = {0.f, 0.f, 0.f, 0.f};
    f32x4 acc1 = {0.f, 0.f, 0.f, 0.f};
#pragma unroll
    for (int ks = 0; ks < 8; ++ks) {
      int o = ks * 32;
      bf16x8 a0h = *(const bf16x8*)(sb + aoff0 + o);
      bf16x8 a1h = *(const bf16x8*)(sb + aoff1 + o);
      bf16x8 a0l = *(const bf16x8*)(sb + ARR + aoff0 + o);
      bf16x8 a1l = *(const bf16x8*)(sb + ARR + aoff1 + o);
      acc0 = __builtin_amdgcn_mfma_f32_16x16x32_bf16(a0h, wh[ks], acc0, 0, 0, 0);
      acc1 = __builtin_amdgcn_mfma_f32_16x16x32_bf16(a1h, wh[ks], acc1, 0, 0, 0);
      acc0 = __builtin_amdgcn_mfma_f32_16x16x32_bf16(a0h, wl[ks], acc0, 0, 0, 0);
      acc1 = __builtin_amdgcn_mfma_f32_16x16x32_bf16(a1h, wl[ks], acc1, 0, 0, 0);
      acc0 = __builtin_amdgcn_mfma_f32_16x16x32_bf16(a0l, wh[ks], acc0, 0, 0, 0);
      acc1 = __builtin_amdgcn_mfma_f32_16x16x32_bf16(a1l, wh[ks], acc1, 0, 0, 0);
    }

    __syncthreads();   // x/dt staged; LDS phase boundary

    // ---- epilogue: D layout row=(oct*4+r) (=b_local within tile), col=n ----
    if (wv == 0) {
      int g = n & 3;
#pragma unroll
      for (int mt = 0; mt < 2; ++mt) {
        f32x4 a = mt ? acc1 : acc0;
#pragma unroll
        for (int r = 0; r < 4; ++r) {
          int bl = mt * 16 + oct * 4 + r;
          float xwv = 0.f;
#pragma unroll
          for (int kk = 0; kk < 12; ++kk) xwv += xs_lds[bl * 12 + kk] * wx[kk];
          float v = a[r] + biasv + xwv;
          float act = (g == 2) ? tanhf(v) : sigmf(v);
          g_lds[bl * 16 + n] = act;
        }
      }
    } else {
#pragma unroll
      for (int mt = 0; mt < 2; ++mt) {
        f32x4 a = mt ? acc1 : acc0;
#pragma unroll
        for (int r = 0; r < 4; ++r) {
          int bl = mt * 16 + oct * 4 + r;
          float v = a[r] + biasv;
          float cs = tanhf(v);
          float dtv = dt_lds[bl * 12 + kd];
          float coef = 1.0f / __logf(2.718281828459045f + dtv) - 1.0f;
          dsum_lds[bl * 48 + jjd * 12 + kd] = cs * coef;
        }
      }
    }
    __syncthreads();

    // ---- state update: tid<32, one batch row each, packed 8B sc1 stores ----
    if (tid < 32) {
      int b = tid;
      union P { unsigned short u[4]; unsigned long long q; } ph, pl, pc, pq;
#pragma unroll
      for (int jj = 0; jj < 4; ++jj) {
        float iv = g_lds[b * 16 + jj * 4 + 0];
        float fv = g_lds[b * 16 + jj * 4 + 1];
        float gv = g_lds[b * 16 + jj * 4 + 2];
        float ov = g_lds[b * 16 + jj * 4 + 3];
        float S = 0.f;
#pragma unroll
        for (int k = 0; k < 12; ++k) S += dsum_lds[b * 48 + jj * 12 + k];
        float cst = c_reg[jj] + S;
        float cn = fv * cst + iv * gv;
        float hn = ov * tanhf(cn);
        c_reg[jj] = cn;
        ph.u[jj] = f2bf(hn);
        pl.u[jj] = f2bf(hn - bf2f(ph.u[jj]));
        pc.u[jj] = f2bf(cn);
        pq.u[jj] = f2bf(cn - bf2f(pc.u[jj]));
        if (t == Tn - 1)
          h_final[(size_t)(bg * 32 + b) * Hn + j0 + jj] = hn;
      }
      unsigned long long* db = (unsigned long long*)state
          + (size_t)((t + 1) & 1) * (SSTRIDE / 4)
          + (size_t)(bg * 32 + b) * 64 + (j0 >> 2);
      __hip_atomic_store(db + 0 * (ARR / 4), ph.q, __ATOMIC_RELAXED, __HIP_MEMORY_SCOPE_AGENT);
      __hip_atomic_store(db + 1 * (ARR / 4), pl.q, __ATOMIC_RELAXED, __HIP_MEMORY_SCOPE_AGENT);
      __hip_atomic_store(db + 2 * (ARR / 4), pc.q, __ATOMIC_RELAXED, __HIP_MEMORY_SCOPE_AGENT);
      __hip_atomic_store(db + 3 * (ARR / 4), pq.q, __ATOMIC_RELAXED, __HIP_MEMORY_SCOPE_AGENT);
    }

    // ---- grid barrier: fence-light. No release (nothing dirty to flush);
    //      relaxed monotone arrival + publish; ONE acquire inv per tid0. ----
    ++gen;
    __syncthreads();   // per-wave s_waitcnt vmcnt(0): all WG stores ack'd at MALL
    if (tid == 0) {
      unsigned old = __hip_atomic_fetch_add(cnt, 1u, __ATOMIC_RELAXED,
                                            __HIP_MEMORY_SCOPE_AGENT);
      if (old == gen * NWG - 1) {
        __hip_atomic_store(flg, gen, __ATOMIC_RELAXED, __HIP_MEMORY_SCOPE_AGENT);
      } else {
        while (__hip_atomic_load(flg, __ATOMIC_RELAXED,
                                 __HIP_MEMORY_SCOPE_AGENT) < gen)
          __builtin_amdgcn_s_sleep(2);
      }
      __builtin_amdgcn_fence(__ATOMIC_ACQUIRE, "agent");  // inv vL1+L2, no wbl2
    }
    __syncthreads();
  }
}

__global__ void out_gemv(const float* __restrict__ hf, const float* __restrict__ lw,
                         const float* __restrict__ lb, float* __restrict__ out)
{
  int b = blockIdx.x;
  int l = threadIdx.x;
  const float* row = hf + b * Hn;
  float s = row[l] * lw[l] + row[l + 64] * lw[l + 64]
          + row[l + 128] * lw[l + 128] + row[l + 192] * lw[l + 192];
#pragma unroll
  for (int off = 32; off > 0; off >>= 1) s += __shfl_down(s, off, 64);
  if (l == 0) out[b] = s + lb[0];
}

extern "C" void kernel_launch(void* const* d_in, const int* in_sizes, int n_in,
                              void* d_out, int out_size, void* d_ws, size_t ws_size,
                              hipStream_t stream)
{
  const float* xd   = (const float*)d_in[0];
  const float* dtp  = (const float*)d_in[1];
  const float* wih  = (const float*)d_in[2];
  const float* whh  = (const float*)d_in[3];
  const float* bias = (const float*)d_in[4];
  const float* wdc  = (const float*)d_in[5];
  const float* bdc  = (const float*)d_in[6];
  const float* lw   = (const float*)d_in[7];
  const float* lb   = (const float*)d_in[8];
  float* out = (float*)d_out;
  unsigned char* ws = (unsigned char*)d_ws;

  // zero barrier + both state buffers (ws is poisoned 0xAA each call)
  hipMemsetAsync(ws, 0, 128 + 2 * SSTRIDE * 2, stream);

  void* args[] = { (void*)&xd, (void*)&dtp, (void*)&wih, (void*)&whh,
                   (void*)&bias, (void*)&wdc, (void*)&bdc, (void*)&ws };
  hipLaunchCooperativeKernel((const void*)mtlstm_kernel, dim3(NWG), dim3(256),
                             args, 0, stream);

  const float* hf = (const float*)(ws + 128 + 2 * SSTRIDE * 2);
  out_gemv<<<dim3(Bn), dim3(64), 0, stream>>>(hf, lw, lb, out);
}